// Round 14
// baseline (410.267 us; speedup 1.0000x reference)
//
#include <hip/hip_runtime.h>

#define NN 4096      // nodes
#define NH 8         // heads
#define BTT 48       // B*T
#define KG 262144    // NN*64 (GEMM K)
#define NJ 512       // 4*Hl
#define HLL 128      // Hl
#define ERAW 65536   // raw edges
#define NKC 256      // GEMM K-split chunks (each 1024)
#define NG  24576    // BTT*NJ

typedef __attribute__((ext_vector_type(8))) short bf16x8;
typedef __attribute__((ext_vector_type(4))) float f32x4;
typedef __attribute__((ext_vector_type(8))) unsigned short ushort8;

__device__ __forceinline__ unsigned short f2bf(float f) {
  unsigned int u = __float_as_uint(f);
  u += 0x7FFFu + ((u >> 16) & 1u);
  return (unsigned short)(u >> 16);
}
__device__ __forceinline__ float bf2f(unsigned short s) {
  return __uint_as_float(((unsigned int)s) << 16);
}
__device__ __forceinline__ float4 nt_load4(const float* p) {
  f32x4 v = __builtin_nontemporal_load((const f32x4*)p);
  return float4{v[0], v[1], v[2], v[3]};
}

// ---------------- fused: proj (blocks 0..6143) + scatter (blocks 6144..6415) ----------------
__global__ __launch_bounds__(256) void k_sp(const float* __restrict__ x, const float* __restrict__ Wg,
                                            const float* __restrict__ att_s, const float* __restrict__ att_d,
                                            const int* __restrict__ ei, int* __restrict__ cursor,
                                            int* __restrict__ ssrc,
                                            unsigned short* __restrict__ h, float* __restrict__ a_s,
                                            float* __restrict__ a_d) {
  int tid = threadIdx.x;
  int bid = blockIdx.x;
  if (bid >= 6144) {
    // ---- scatter: edges + self-loops into fixed-capacity buckets (cursor pre-zeroed) ----
    int t = (bid - 6144) * 256 + tid;   // 0..69631
    if (t < ERAW) {
      int s = ei[t], d = ei[ERAW + t];
      int pos = atomicAdd(&cursor[d], 1);
      ssrc[(d << 6) + pos] = s;
    } else {
      int n = t - ERAW;                  // 4096 self-loops
      int pos = atomicAdd(&cursor[n], 1);
      ssrc[(n << 6) + pos] = n;
    }
    return;
  }
  // ---- proj ----
  __shared__ float wgs[512];
  __shared__ float ats[64], atd[64];
  wgs[tid] = Wg[tid];
  wgs[256 + tid] = Wg[256 + tid];
  if (tid < 64) { ats[tid] = att_s[tid]; atd[tid] = att_d[tid]; }
  __syncthreads();
  int bt = bid >> 7;
  int inner = bid & 127;
  int hd = tid & 7, nl = tid >> 3;
  int n = inner * 32 + nl;
  const float* xr = x + ((size_t)(bt * NN + n)) * 8;
  float4 xa = *(const float4*)xr, xb2 = *(const float4*)(xr + 4);
  float xv[8] = {xa.x, xa.y, xa.z, xa.w, xb2.x, xb2.y, xb2.z, xb2.w};
  int hb = hd * 8;
  float hv[8];
#pragma unroll
  for (int c = 0; c < 8; ++c) {
    float acc = 0.f;
#pragma unroll
    for (int f = 0; f < 8; ++f) acc += xv[f] * wgs[f * 64 + hb + c];
    hv[c] = acc;
  }
  float as = 0.f, ad = 0.f;
#pragma unroll
  for (int c = 0; c < 8; ++c) { as += hv[c] * ats[hb + c]; ad += hv[c] * atd[hb + c]; }
  int aoff = bt * (NN * NH) + n * NH + hd;
  a_s[aoff] = as;
  a_d[aoff] = ad;
  ushort8 hr;
#pragma unroll
  for (int c = 0; c < 8; ++c) hr[c] = f2bf(hv[c]);
  *(ushort8*)(h + (size_t)bt * KG + (size_t)n * 64 + hb) = hr;
}

// ---------------- GAT aggregation, bt->XCD pinned, bucket CSR, no max-shift ----------------
__global__ __launch_bounds__(256) void k_gat(const unsigned short* __restrict__ h, const float* __restrict__ a_s,
                                             const float* __restrict__ a_d, const int* __restrict__ cursor,
                                             const int* __restrict__ ssrc, const float* __restrict__ b_gat,
                                             unsigned short* __restrict__ Xb) {
  int B = blockIdx.x;
  int xcd = B & 7;
  int slot = B >> 3;            // 0..767
  int btg = slot >> 7;          // 0..5
  int inner = slot & 127;       // 0..127
  int bt = btg * 8 + xcd;       // all 128 blocks of bt share B&7
  int tid = threadIdx.x;
  int hd = tid & 7, nl = tid >> 3;
  int n = inner * 32 + nl;
  const unsigned short* hbase = h + (size_t)bt * KG;
  const float* asb = a_s + bt * (NN * NH);
  float adn = a_d[bt * (NN * NH) + n * NH + hd];
  int deg = cursor[n];
  const int* bucket = ssrc + (n << 6);
  float ssum = 0.f;
  float o[8];
#pragma unroll
  for (int c = 0; c < 8; ++c) o[c] = 0.f;
  for (int i = 0; i < deg; ++i) {
    int s = bucket[i];
    float e = asb[s * NH + hd] + adn;
    e = (e > 0.f) ? e : 0.2f * e;  // leaky_relu(0.2)
    float p = __expf(e);           // |e| <= ~8: no overflow, max-shift not needed
    ssum += p;
    ushort8 hvv = *(const ushort8*)(hbase + (size_t)s * 64 + hd * 8);
#pragma unroll
    for (int c = 0; c < 8; ++c) o[c] += p * bf2f(hvv[c]);
  }
  float inv = 1.f / ssum;
  ushort8 r;
#pragma unroll
  for (int c = 0; c < 8; ++c) {
    float v = o[c] * inv + b_gat[hd * 8 + c];
    v = (v > 0.f) ? v : (__expf(v) - 1.f);  // ELU
    r[c] = f2bf(v);
  }
  *(ushort8*)(Xb + (size_t)bt * KG + (size_t)n * 64 + hd * 8) = r;
}

// ---------------- big skinny GEMM: Gp8[kc>>5][48][512] += X*W^T (sliced atomic epilogue) ----------------
// 8 partial copies cut per-address atomic contention 256 -> 32 writers.
__global__ __launch_bounds__(256) void k_gemm(const unsigned short* __restrict__ Xb,
                                              const float* __restrict__ Wih, float* __restrict__ Gp8) {
  int tid = threadIdx.x;
  int w = tid >> 6, lane = tid & 63;
  int lm = lane & 15, kg = lane >> 4;
  int jb = blockIdx.x & 3;       // 4 j-blocks of 128
  int kc = blockIdx.x >> 2;      // 256 k-chunks of 1024
  int j0 = jb * 128 + w * 32;    // this wave's 32 W-rows
  size_t kbase = (size_t)kc * 1024 + kg * 8;

  const float* wr0 = Wih + (size_t)(j0 + lm) * KG + kbase;        // jf=0 rows
  const float* wr1 = Wih + (size_t)(j0 + 16 + lm) * KG + kbase;   // jf=1 rows
  const short* Xs = (const short*)Xb;
  const short* xr0 = Xs + (size_t)lm * KG + kbase;
  const short* xr1 = xr0 + (size_t)16 * KG;
  const short* xr2 = xr0 + (size_t)32 * KG;

  f32x4 acc[3][2];
#pragma unroll
  for (int mf = 0; mf < 3; ++mf)
#pragma unroll
    for (int jf = 0; jf < 2; ++jf) acc[mf][jf] = f32x4{0.f, 0.f, 0.f, 0.f};

  float4 wbuf[2][4];   // [buf][jf*2+half]
  bf16x8 abuf[2][3];   // [buf][mf]

  wbuf[0][0] = nt_load4(wr0);
  wbuf[0][1] = nt_load4(wr0 + 4);
  wbuf[0][2] = nt_load4(wr1);
  wbuf[0][3] = nt_load4(wr1 + 4);
  abuf[0][0] = *(const bf16x8*)(xr0);
  abuf[0][1] = *(const bf16x8*)(xr1);
  abuf[0][2] = *(const bf16x8*)(xr2);

#pragma unroll 2
  for (int t = 0; t < 32; ++t) {
    int cur = t & 1, nxt = cur ^ 1;
    if (t + 1 < 32) {
      int off = (t + 1) * 32;
      wbuf[nxt][0] = nt_load4(wr0 + off);
      wbuf[nxt][1] = nt_load4(wr0 + off + 4);
      wbuf[nxt][2] = nt_load4(wr1 + off);
      wbuf[nxt][3] = nt_load4(wr1 + off + 4);
      abuf[nxt][0] = *(const bf16x8*)(xr0 + off);
      abuf[nxt][1] = *(const bf16x8*)(xr1 + off);
      abuf[nxt][2] = *(const bf16x8*)(xr2 + off);
    }
#pragma unroll
    for (int jf = 0; jf < 2; ++jf) {
      float4 f0 = wbuf[cur][jf * 2], f1 = wbuf[cur][jf * 2 + 1];
      bf16x8 bb;
      bb[0] = (short)f2bf(f0.x); bb[1] = (short)f2bf(f0.y);
      bb[2] = (short)f2bf(f0.z); bb[3] = (short)f2bf(f0.w);
      bb[4] = (short)f2bf(f1.x); bb[5] = (short)f2bf(f1.y);
      bb[6] = (short)f2bf(f1.z); bb[7] = (short)f2bf(f1.w);
      acc[0][jf] = __builtin_amdgcn_mfma_f32_16x16x32_bf16(abuf[cur][0], bb, acc[0][jf], 0, 0, 0);
      acc[1][jf] = __builtin_amdgcn_mfma_f32_16x16x32_bf16(abuf[cur][1], bb, acc[1][jf], 0, 0, 0);
      acc[2][jf] = __builtin_amdgcn_mfma_f32_16x16x32_bf16(abuf[cur][2], bb, acc[2][jf], 0, 0, 0);
    }
  }

  // epilogue: atomic accumulate into Gp8[kc>>5][bt][j]
  float* gout = Gp8 + (size_t)(kc >> 5) * NG;
#pragma unroll
  for (int mf = 0; mf < 3; ++mf)
#pragma unroll
    for (int jf = 0; jf < 2; ++jf) {
      int j = j0 + jf * 16 + lm;
#pragma unroll
      for (int r = 0; r < 4; ++r) {
        int bt = mf * 16 + kg * 4 + r;   // C/D: col=lane&15, row=(lane>>4)*4+r
        atomicAdd(&gout[bt * NJ + j], acc[mf][jf][r]);
      }
    }
}

// ---------------- fused LSTM + FC (64 blocks x 512 threads) ----------------
// Each block redundantly computes the 4-batch LSTM (thread j holds Whh row j in regs,
// proven k_lstm structure), stores hlast in LDS, then does its 512-column FC slice.
// Redundant LSTM ~9us serial-bound; removes one dispatch gap (~15us).
__global__ __launch_bounds__(512) void k_tail(const float* __restrict__ Gp8, const float* __restrict__ Whh,
                                              const float* __restrict__ bih, const float* __restrict__ bhh,
                                              const float* __restrict__ Wfc, const float* __restrict__ bfc,
                                              float* __restrict__ out) {
  __shared__ float hs[HLL];
  __shared__ float gs[NJ];
  __shared__ float hl[4 * HLL];
  int j = threadIdx.x;
  float bias = bih[j] + bhh[j];
  float w[HLL];
  const float* wr = Whh + (size_t)j * HLL;
#pragma unroll
  for (int k = 0; k < HLL; k += 4) {
    float4 v = *(const float4*)(wr + k);
    w[k] = v.x; w[k + 1] = v.y; w[k + 2] = v.z; w[k + 3] = v.w;
  }
  for (int b = 0; b < 4; ++b) {
    if (j < HLL) hs[j] = 0.f;
    float c = 0.f;
    __syncthreads();
    for (int t = 0; t < 12; ++t) {
      const float* gp = Gp8 + (size_t)(b * 12 + t) * NJ + j;
      float acc = bias;
#pragma unroll
      for (int s = 0; s < 8; ++s) acc += gp[(size_t)s * NG];   // sum 8 sliced partials
#pragma unroll
      for (int k = 0; k < HLL; ++k) acc += w[k] * hs[k];
      gs[j] = acc;
      __syncthreads();
      if (j < HLL) {
        float gi = gs[j], gf = gs[HLL + j], gg = gs[2 * HLL + j], go = gs[3 * HLL + j];
        float si = 1.f / (1.f + __expf(-gi));
        float sf = 1.f / (1.f + __expf(-gf));
        float so = 1.f / (1.f + __expf(-go));
        c = sf * c + si * tanhf(gg);
        hs[j] = so * tanhf(c);
      }
      __syncthreads();
    }
    if (j < HLL) hl[b * HLL + j] = hs[j];
    __syncthreads();
  }
  // FC slice: n = bid*512 + j
  int n = blockIdx.x * 512 + j;
  float a0 = 0.f, a1 = 0.f, a2 = 0.f, a3 = 0.f;
#pragma unroll 8
  for (int k = 0; k < HLL; ++k) {
    float wv = Wfc[(size_t)k * 32768 + n];
    a0 += hl[k] * wv;
    a1 += hl[HLL + k] * wv;
    a2 += hl[2 * HLL + k] * wv;
    a3 += hl[3 * HLL + k] * wv;
  }
  float bb = bfc[n];
  out[n] = a0 + bb;
  out[32768 + n] = a1 + bb;
  out[65536 + n] = a2 + bb;
  out[98304 + n] = a3 + bb;
}

extern "C" void kernel_launch(void* const* d_in, const int* in_sizes, int n_in,
                              void* d_out, int out_size, void* d_ws, size_t ws_size,
                              hipStream_t stream) {
  const float* x     = (const float*)d_in[0];
  const int*   ei    = (const int*)d_in[1];   // int32 (JAX x64 off)
  const float* Wg    = (const float*)d_in[2];
  const float* att_s = (const float*)d_in[3];
  const float* att_d = (const float*)d_in[4];
  const float* b_gat = (const float*)d_in[5];
  const float* Wih   = (const float*)d_in[6];
  const float* Whh   = (const float*)d_in[7];
  const float* bih   = (const float*)d_in[8];
  const float* bhh   = (const float*)d_in[9];
  const float* Wfc   = (const float*)d_in[10];
  const float* bfc   = (const float*)d_in[11];
  float* out = (float*)d_out;

  char* ws = (char*)d_ws;
  unsigned short* h  = (unsigned short*)(ws);      // bf16: 48*4096*64*2 = 25165824
  float* a_s         = (float*)(ws + 25165824);    // 6291456
  float* a_d         = (float*)(ws + 31457280);    // 6291456
  unsigned short* Xb = (unsigned short*)(ws + 37748736); // 25165824 (ends 62914560)
  int* ssrc          = (int*)(ws + 62914560);      // 4096*64*4 = 1048576 (ends 63963136)
  int* cursor        = (int*)(ws + 63963136);      // 16384 (ends 63979520)
  float* Gp8         = (float*)(ws + 63979520);    // 8*24576*4 = 786432 (ends 64765952)

  // one memset covers cursor + Gp8 (contiguous)
  hipMemsetAsync(cursor, 0, 16384 + 786432, stream);
  hipLaunchKernelGGL(k_sp,   dim3(6416),     dim3(256), 0, stream, x, Wg, att_s, att_d, ei, cursor, ssrc, h, a_s, a_d);
  hipLaunchKernelGGL(k_gat,  dim3(48 * 128), dim3(256), 0, stream, h, a_s, a_d, cursor, ssrc, b_gat, Xb);
  hipLaunchKernelGGL(k_gemm, dim3(1024),     dim3(256), 0, stream, Xb, Wih, Gp8);
  hipLaunchKernelGGL(k_tail, dim3(64),       dim3(512), 0, stream, Gp8, Whh, bih, bhh, Wfc, bfc, out);
}

// Round 15
// 343.298 us; speedup vs baseline: 1.1951x; 1.1951x over previous
//
#include <hip/hip_runtime.h>

#define NN 4096      // nodes
#define NH 8         // heads
#define BTT 48       // B*T
#define KG 262144    // NN*64 (GEMM K)
#define NJ 512       // 4*Hl
#define HLL 128      // Hl
#define ERAW 65536   // raw edges
#define NKC 256      // GEMM K-split chunks (each 1024)
#define NG  24576    // BTT*NJ

typedef __attribute__((ext_vector_type(8))) short bf16x8;
typedef __attribute__((ext_vector_type(4))) float f32x4;
typedef __attribute__((ext_vector_type(8))) unsigned short ushort8;

__device__ __forceinline__ unsigned short f2bf(float f) {
  unsigned int u = __float_as_uint(f);
  u += 0x7FFFu + ((u >> 16) & 1u);
  return (unsigned short)(u >> 16);
}
__device__ __forceinline__ float bf2f(unsigned short s) {
  return __uint_as_float(((unsigned int)s) << 16);
}
__device__ __forceinline__ float4 nt_load4(const float* p) {
  f32x4 v = __builtin_nontemporal_load((const f32x4*)p);
  return float4{v[0], v[1], v[2], v[3]};
}

// ---------------- fused: proj (blocks 0..6143) + scatter & G-zero (blocks 6144..6415) ----------------
__global__ __launch_bounds__(256) void k_sp(const float* __restrict__ x, const float* __restrict__ Wg,
                                            const float* __restrict__ att_s, const float* __restrict__ att_d,
                                            const int* __restrict__ ei, int* __restrict__ cursor,
                                            int* __restrict__ ssrc, float* __restrict__ G,
                                            unsigned short* __restrict__ h, float* __restrict__ a_s,
                                            float* __restrict__ a_d) {
  int tid = threadIdx.x;
  int bid = blockIdx.x;
  if (bid >= 6144) {
    // ---- scatter: edges + self-loops into fixed-capacity buckets; also zero G ----
    int t = (bid - 6144) * 256 + tid;   // 0..69631
    if (t < NG) G[t] = 0.f;             // zero GEMM accumulator (atomics target)
    if (t < ERAW) {
      int s = ei[t], d = ei[ERAW + t];
      int pos = atomicAdd(&cursor[d], 1);
      ssrc[(d << 6) + pos] = s;
    } else {
      int n = t - ERAW;                  // 4096 self-loops
      int pos = atomicAdd(&cursor[n], 1);
      ssrc[(n << 6) + pos] = n;
    }
    return;
  }
  // ---- proj ----
  __shared__ float wgs[512];
  __shared__ float ats[64], atd[64];
  wgs[tid] = Wg[tid];
  wgs[256 + tid] = Wg[256 + tid];
  if (tid < 64) { ats[tid] = att_s[tid]; atd[tid] = att_d[tid]; }
  __syncthreads();
  int bt = bid >> 7;
  int inner = bid & 127;
  int hd = tid & 7, nl = tid >> 3;
  int n = inner * 32 + nl;
  const float* xr = x + ((size_t)(bt * NN + n)) * 8;
  float4 xa = *(const float4*)xr, xb2 = *(const float4*)(xr + 4);
  float xv[8] = {xa.x, xa.y, xa.z, xa.w, xb2.x, xb2.y, xb2.z, xb2.w};
  int hb = hd * 8;
  float hv[8];
#pragma unroll
  for (int c = 0; c < 8; ++c) {
    float acc = 0.f;
#pragma unroll
    for (int f = 0; f < 8; ++f) acc += xv[f] * wgs[f * 64 + hb + c];
    hv[c] = acc;
  }
  float as = 0.f, ad = 0.f;
#pragma unroll
  for (int c = 0; c < 8; ++c) { as += hv[c] * ats[hb + c]; ad += hv[c] * atd[hb + c]; }
  int aoff = bt * (NN * NH) + n * NH + hd;
  a_s[aoff] = as;
  a_d[aoff] = ad;
  ushort8 hr;
#pragma unroll
  for (int c = 0; c < 8; ++c) hr[c] = f2bf(hv[c]);
  *(ushort8*)(h + (size_t)bt * KG + (size_t)n * 64 + hb) = hr;
}

// ---------------- GAT aggregation, bt->XCD pinned, bucket CSR, no max-shift ----------------
__global__ __launch_bounds__(256) void k_gat(const unsigned short* __restrict__ h, const float* __restrict__ a_s,
                                             const float* __restrict__ a_d, const int* __restrict__ cursor,
                                             const int* __restrict__ ssrc, const float* __restrict__ b_gat,
                                             unsigned short* __restrict__ Xb) {
  int B = blockIdx.x;
  int xcd = B & 7;
  int slot = B >> 3;            // 0..767
  int btg = slot >> 7;          // 0..5
  int inner = slot & 127;       // 0..127
  int bt = btg * 8 + xcd;       // all 128 blocks of bt share B&7
  int tid = threadIdx.x;
  int hd = tid & 7, nl = tid >> 3;
  int n = inner * 32 + nl;
  const unsigned short* hbase = h + (size_t)bt * KG;
  const float* asb = a_s + bt * (NN * NH);
  float adn = a_d[bt * (NN * NH) + n * NH + hd];
  int deg = cursor[n];
  const int* bucket = ssrc + (n << 6);
  float ssum = 0.f;
  float o[8];
#pragma unroll
  for (int c = 0; c < 8; ++c) o[c] = 0.f;
  for (int i = 0; i < deg; ++i) {
    int s = bucket[i];
    float e = asb[s * NH + hd] + adn;
    e = (e > 0.f) ? e : 0.2f * e;  // leaky_relu(0.2)
    float p = __expf(e);           // |e| <= ~8: no overflow, max-shift not needed
    ssum += p;
    ushort8 hvv = *(const ushort8*)(hbase + (size_t)s * 64 + hd * 8);
#pragma unroll
    for (int c = 0; c < 8; ++c) o[c] += p * bf2f(hvv[c]);
  }
  float inv = 1.f / ssum;
  ushort8 r;
#pragma unroll
  for (int c = 0; c < 8; ++c) {
    float v = o[c] * inv + b_gat[hd * 8 + c];
    v = (v > 0.f) ? v : (__expf(v) - 1.f);  // ELU
    r[c] = f2bf(v);
  }
  *(ushort8*)(Xb + (size_t)bt * KG + (size_t)n * 64 + hd * 8) = r;
}

// ---------------- big skinny GEMM: G[48][512] += X[48,Kc] * Wih[512,Kc]^T (atomic epilogue, R13) ----------------
__global__ __launch_bounds__(256) void k_gemm(const unsigned short* __restrict__ Xb,
                                              const float* __restrict__ Wih, float* __restrict__ G) {
  int tid = threadIdx.x;
  int w = tid >> 6, lane = tid & 63;
  int lm = lane & 15, kg = lane >> 4;
  int jb = blockIdx.x & 3;       // 4 j-blocks of 128
  int kc = blockIdx.x >> 2;      // 256 k-chunks of 1024
  int j0 = jb * 128 + w * 32;    // this wave's 32 W-rows
  size_t kbase = (size_t)kc * 1024 + kg * 8;

  const float* wr0 = Wih + (size_t)(j0 + lm) * KG + kbase;        // jf=0 rows
  const float* wr1 = Wih + (size_t)(j0 + 16 + lm) * KG + kbase;   // jf=1 rows
  const short* Xs = (const short*)Xb;
  const short* xr0 = Xs + (size_t)lm * KG + kbase;
  const short* xr1 = xr0 + (size_t)16 * KG;
  const short* xr2 = xr0 + (size_t)32 * KG;

  f32x4 acc[3][2];
#pragma unroll
  for (int mf = 0; mf < 3; ++mf)
#pragma unroll
    for (int jf = 0; jf < 2; ++jf) acc[mf][jf] = f32x4{0.f, 0.f, 0.f, 0.f};

  float4 wbuf[2][4];   // [buf][jf*2+half]
  bf16x8 abuf[2][3];   // [buf][mf]

  wbuf[0][0] = nt_load4(wr0);
  wbuf[0][1] = nt_load4(wr0 + 4);
  wbuf[0][2] = nt_load4(wr1);
  wbuf[0][3] = nt_load4(wr1 + 4);
  abuf[0][0] = *(const bf16x8*)(xr0);
  abuf[0][1] = *(const bf16x8*)(xr1);
  abuf[0][2] = *(const bf16x8*)(xr2);

#pragma unroll 2
  for (int t = 0; t < 32; ++t) {
    int cur = t & 1, nxt = cur ^ 1;
    if (t + 1 < 32) {
      int off = (t + 1) * 32;
      wbuf[nxt][0] = nt_load4(wr0 + off);
      wbuf[nxt][1] = nt_load4(wr0 + off + 4);
      wbuf[nxt][2] = nt_load4(wr1 + off);
      wbuf[nxt][3] = nt_load4(wr1 + off + 4);
      abuf[nxt][0] = *(const bf16x8*)(xr0 + off);
      abuf[nxt][1] = *(const bf16x8*)(xr1 + off);
      abuf[nxt][2] = *(const bf16x8*)(xr2 + off);
    }
#pragma unroll
    for (int jf = 0; jf < 2; ++jf) {
      float4 f0 = wbuf[cur][jf * 2], f1 = wbuf[cur][jf * 2 + 1];
      bf16x8 bb;
      bb[0] = (short)f2bf(f0.x); bb[1] = (short)f2bf(f0.y);
      bb[2] = (short)f2bf(f0.z); bb[3] = (short)f2bf(f0.w);
      bb[4] = (short)f2bf(f1.x); bb[5] = (short)f2bf(f1.y);
      bb[6] = (short)f2bf(f1.z); bb[7] = (short)f2bf(f1.w);
      acc[0][jf] = __builtin_amdgcn_mfma_f32_16x16x32_bf16(abuf[cur][0], bb, acc[0][jf], 0, 0, 0);
      acc[1][jf] = __builtin_amdgcn_mfma_f32_16x16x32_bf16(abuf[cur][1], bb, acc[1][jf], 0, 0, 0);
      acc[2][jf] = __builtin_amdgcn_mfma_f32_16x16x32_bf16(abuf[cur][2], bb, acc[2][jf], 0, 0, 0);
    }
  }

  // epilogue: atomic accumulate into G[bt][j]
#pragma unroll
  for (int mf = 0; mf < 3; ++mf)
#pragma unroll
    for (int jf = 0; jf < 2; ++jf) {
      int j = j0 + jf * 16 + lm;
#pragma unroll
      for (int r = 0; r < 4; ++r) {
        int bt = mf * 16 + kg * 4 + r;   // C/D: col=lane&15, row=(lane>>4)*4+r
        atomicAdd(&G[bt * NJ + j], acc[mf][jf][r]);
      }
    }
}

// ---------------- fused LSTM + FC (64 blocks x 512 threads), G read directly ----------------
// Each block redundantly runs the 4-batch LSTM with R13's exact k_lstm memory pattern
// (ONE G load per serial step), stores hlast in LDS, then does its 512-column FC slice.
__global__ __launch_bounds__(512) void k_tail(const float* __restrict__ G, const float* __restrict__ Whh,
                                              const float* __restrict__ bih, const float* __restrict__ bhh,
                                              const float* __restrict__ Wfc, const float* __restrict__ bfc,
                                              float* __restrict__ out) {
  __shared__ float hs[HLL];
  __shared__ float gs[NJ];
  __shared__ float hl[4 * HLL];
  int j = threadIdx.x;
  float bias = bih[j] + bhh[j];
  float w[HLL];
  const float* wr = Whh + (size_t)j * HLL;
#pragma unroll
  for (int k = 0; k < HLL; k += 4) {
    float4 v = *(const float4*)(wr + k);
    w[k] = v.x; w[k + 1] = v.y; w[k + 2] = v.z; w[k + 3] = v.w;
  }
  for (int b = 0; b < 4; ++b) {
    if (j < HLL) hs[j] = 0.f;
    float c = 0.f;
    __syncthreads();
    for (int t = 0; t < 12; ++t) {
      float acc = G[(size_t)(b * 12 + t) * NJ + j] + bias;
#pragma unroll
      for (int k = 0; k < HLL; ++k) acc += w[k] * hs[k];
      gs[j] = acc;
      __syncthreads();
      if (j < HLL) {
        float gi = gs[j], gf = gs[HLL + j], gg = gs[2 * HLL + j], go = gs[3 * HLL + j];
        float si = 1.f / (1.f + __expf(-gi));
        float sf = 1.f / (1.f + __expf(-gf));
        float so = 1.f / (1.f + __expf(-go));
        c = sf * c + si * tanhf(gg);
        hs[j] = so * tanhf(c);
      }
      __syncthreads();
    }
    if (j < HLL) hl[b * HLL + j] = hs[j];
    __syncthreads();
  }
  // FC slice: n = bid*512 + j
  int n = blockIdx.x * 512 + j;
  float a0 = 0.f, a1 = 0.f, a2 = 0.f, a3 = 0.f;
#pragma unroll 8
  for (int k = 0; k < HLL; ++k) {
    float wv = Wfc[(size_t)k * 32768 + n];
    a0 += hl[k] * wv;
    a1 += hl[HLL + k] * wv;
    a2 += hl[2 * HLL + k] * wv;
    a3 += hl[3 * HLL + k] * wv;
  }
  float bb = bfc[n];
  out[n] = a0 + bb;
  out[32768 + n] = a1 + bb;
  out[65536 + n] = a2 + bb;
  out[98304 + n] = a3 + bb;
}

extern "C" void kernel_launch(void* const* d_in, const int* in_sizes, int n_in,
                              void* d_out, int out_size, void* d_ws, size_t ws_size,
                              hipStream_t stream) {
  const float* x     = (const float*)d_in[0];
  const int*   ei    = (const int*)d_in[1];   // int32 (JAX x64 off)
  const float* Wg    = (const float*)d_in[2];
  const float* att_s = (const float*)d_in[3];
  const float* att_d = (const float*)d_in[4];
  const float* b_gat = (const float*)d_in[5];
  const float* Wih   = (const float*)d_in[6];
  const float* Whh   = (const float*)d_in[7];
  const float* bih   = (const float*)d_in[8];
  const float* bhh   = (const float*)d_in[9];
  const float* Wfc   = (const float*)d_in[10];
  const float* bfc   = (const float*)d_in[11];
  float* out = (float*)d_out;

  char* ws = (char*)d_ws;
  unsigned short* h  = (unsigned short*)(ws);      // bf16: 48*4096*64*2 = 25165824
  float* a_s         = (float*)(ws + 25165824);    // 6291456
  float* a_d         = (float*)(ws + 31457280);    // 6291456
  unsigned short* Xb = (unsigned short*)(ws + 37748736); // 25165824 (ends 62914560)
  int* ssrc          = (int*)(ws + 62914560);      // 4096*64*4 = 1048576
  float* G           = (float*)(ws + 63963136);    // 24576*4   = 98304
  float* hlast       = (float*)(ws + 64061440);    // 2048 (unused this round)
  int* cursor        = (int*)(ws + 64063488);      // 16384

  hipMemsetAsync(cursor, 0, NN * sizeof(int), stream);
  hipLaunchKernelGGL(k_sp,   dim3(6416),     dim3(256), 0, stream, x, Wg, att_s, att_d, ei, cursor, ssrc, G, h, a_s, a_d);
  hipLaunchKernelGGL(k_gat,  dim3(48 * 128), dim3(256), 0, stream, h, a_s, a_d, cursor, ssrc, b_gat, Xb);
  hipLaunchKernelGGL(k_gemm, dim3(1024),     dim3(256), 0, stream, Xb, Wih, G);
  hipLaunchKernelGGL(k_tail, dim3(64),       dim3(512), 0, stream, G, Whh, bih, bhh, Wfc, bfc, out);
  (void)hlast;
}

// Round 16
// 286.038 us; speedup vs baseline: 1.4343x; 1.2002x over previous
//
#include <hip/hip_runtime.h>

#define NN 4096      // nodes
#define NH 8         // heads
#define BTT 48       // B*T
#define KG 262144    // NN*64 (GEMM K)
#define NJ 512       // 4*Hl
#define HLL 128      // Hl
#define ERAW 65536   // raw edges
#define NKC 256      // GEMM K-split chunks (each 1024)
#define NG  24576    // BTT*NJ

typedef __attribute__((ext_vector_type(8))) short bf16x8;
typedef __attribute__((ext_vector_type(4))) float f32x4;
typedef __attribute__((ext_vector_type(8))) unsigned short ushort8;

__device__ __forceinline__ unsigned short f2bf(float f) {
  unsigned int u = __float_as_uint(f);
  u += 0x7FFFu + ((u >> 16) & 1u);
  return (unsigned short)(u >> 16);
}
__device__ __forceinline__ float bf2f(unsigned short s) {
  return __uint_as_float(((unsigned int)s) << 16);
}
__device__ __forceinline__ float4 nt_load4(const float* p) {
  f32x4 v = __builtin_nontemporal_load((const f32x4*)p);
  return float4{v[0], v[1], v[2], v[3]};
}

// ---------------- fused: proj (blocks 0..6143) + scatter & G-zero (blocks 6144..6415) ----------------
__global__ __launch_bounds__(256) void k_sp(const float* __restrict__ x, const float* __restrict__ Wg,
                                            const float* __restrict__ att_s, const float* __restrict__ att_d,
                                            const int* __restrict__ ei, int* __restrict__ cursor,
                                            int* __restrict__ ssrc, float* __restrict__ G,
                                            unsigned short* __restrict__ h, float* __restrict__ a_s,
                                            float* __restrict__ a_d) {
  int tid = threadIdx.x;
  int bid = blockIdx.x;
  if (bid >= 6144) {
    // ---- scatter: edges + self-loops into fixed-capacity buckets; also zero G ----
    int t = (bid - 6144) * 256 + tid;   // 0..69631
    if (t < NG) G[t] = 0.f;             // zero GEMM accumulator (atomics target)
    if (t < ERAW) {
      int s = ei[t], d = ei[ERAW + t];
      int pos = atomicAdd(&cursor[d], 1);
      ssrc[(d << 6) + pos] = s;
    } else {
      int n = t - ERAW;                  // 4096 self-loops
      int pos = atomicAdd(&cursor[n], 1);
      ssrc[(n << 6) + pos] = n;
    }
    return;
  }
  // ---- proj ----
  __shared__ float wgs[512];
  __shared__ float ats[64], atd[64];
  wgs[tid] = Wg[tid];
  wgs[256 + tid] = Wg[256 + tid];
  if (tid < 64) { ats[tid] = att_s[tid]; atd[tid] = att_d[tid]; }
  __syncthreads();
  int bt = bid >> 7;
  int inner = bid & 127;
  int hd = tid & 7, nl = tid >> 3;
  int n = inner * 32 + nl;
  const float* xr = x + ((size_t)(bt * NN + n)) * 8;
  float4 xa = *(const float4*)xr, xb2 = *(const float4*)(xr + 4);
  float xv[8] = {xa.x, xa.y, xa.z, xa.w, xb2.x, xb2.y, xb2.z, xb2.w};
  int hb = hd * 8;
  float hv[8];
#pragma unroll
  for (int c = 0; c < 8; ++c) {
    float acc = 0.f;
#pragma unroll
    for (int f = 0; f < 8; ++f) acc += xv[f] * wgs[f * 64 + hb + c];
    hv[c] = acc;
  }
  float as = 0.f, ad = 0.f;
#pragma unroll
  for (int c = 0; c < 8; ++c) { as += hv[c] * ats[hb + c]; ad += hv[c] * atd[hb + c]; }
  int aoff = bt * (NN * NH) + n * NH + hd;
  a_s[aoff] = as;
  a_d[aoff] = ad;
  ushort8 hr;
#pragma unroll
  for (int c = 0; c < 8; ++c) hr[c] = f2bf(hv[c]);
  *(ushort8*)(h + (size_t)bt * KG + (size_t)n * 64 + hb) = hr;
}

// ---------------- GAT aggregation, bt->XCD pinned, bucket CSR, no max-shift ----------------
__global__ __launch_bounds__(256) void k_gat(const unsigned short* __restrict__ h, const float* __restrict__ a_s,
                                             const float* __restrict__ a_d, const int* __restrict__ cursor,
                                             const int* __restrict__ ssrc, const float* __restrict__ b_gat,
                                             unsigned short* __restrict__ Xb) {
  int B = blockIdx.x;
  int xcd = B & 7;
  int slot = B >> 3;            // 0..767
  int btg = slot >> 7;          // 0..5
  int inner = slot & 127;       // 0..127
  int bt = btg * 8 + xcd;       // all 128 blocks of bt share B&7
  int tid = threadIdx.x;
  int hd = tid & 7, nl = tid >> 3;
  int n = inner * 32 + nl;
  const unsigned short* hbase = h + (size_t)bt * KG;
  const float* asb = a_s + bt * (NN * NH);
  float adn = a_d[bt * (NN * NH) + n * NH + hd];
  int deg = cursor[n];
  const int* bucket = ssrc + (n << 6);
  float ssum = 0.f;
  float o[8];
#pragma unroll
  for (int c = 0; c < 8; ++c) o[c] = 0.f;
  for (int i = 0; i < deg; ++i) {
    int s = bucket[i];
    float e = asb[s * NH + hd] + adn;
    e = (e > 0.f) ? e : 0.2f * e;  // leaky_relu(0.2)
    float p = __expf(e);           // |e| <= ~8: no overflow, max-shift not needed
    ssum += p;
    ushort8 hvv = *(const ushort8*)(hbase + (size_t)s * 64 + hd * 8);
#pragma unroll
    for (int c = 0; c < 8; ++c) o[c] += p * bf2f(hvv[c]);
  }
  float inv = 1.f / ssum;
  ushort8 r;
#pragma unroll
  for (int c = 0; c < 8; ++c) {
    float v = o[c] * inv + b_gat[hd * 8 + c];
    v = (v > 0.f) ? v : (__expf(v) - 1.f);  // ELU
    r[c] = f2bf(v);
  }
  *(ushort8*)(Xb + (size_t)bt * KG + (size_t)n * 64 + hd * 8) = r;
}

// ---------------- big skinny GEMM: G[48][512] += X[48,Kc] * Wih[512,Kc]^T (atomic epilogue) ----------------
__global__ __launch_bounds__(256) void k_gemm(const unsigned short* __restrict__ Xb,
                                              const float* __restrict__ Wih, float* __restrict__ G) {
  int tid = threadIdx.x;
  int w = tid >> 6, lane = tid & 63;
  int lm = lane & 15, kg = lane >> 4;
  int jb = blockIdx.x & 3;       // 4 j-blocks of 128
  int kc = blockIdx.x >> 2;      // 256 k-chunks of 1024
  int j0 = jb * 128 + w * 32;    // this wave's 32 W-rows
  size_t kbase = (size_t)kc * 1024 + kg * 8;

  const float* wr0 = Wih + (size_t)(j0 + lm) * KG + kbase;        // jf=0 rows
  const float* wr1 = Wih + (size_t)(j0 + 16 + lm) * KG + kbase;   // jf=1 rows
  const short* Xs = (const short*)Xb;
  const short* xr0 = Xs + (size_t)lm * KG + kbase;
  const short* xr1 = xr0 + (size_t)16 * KG;
  const short* xr2 = xr0 + (size_t)32 * KG;

  f32x4 acc[3][2];
#pragma unroll
  for (int mf = 0; mf < 3; ++mf)
#pragma unroll
    for (int jf = 0; jf < 2; ++jf) acc[mf][jf] = f32x4{0.f, 0.f, 0.f, 0.f};

  float4 wbuf[2][4];   // [buf][jf*2+half]
  bf16x8 abuf[2][3];   // [buf][mf]

  wbuf[0][0] = nt_load4(wr0);
  wbuf[0][1] = nt_load4(wr0 + 4);
  wbuf[0][2] = nt_load4(wr1);
  wbuf[0][3] = nt_load4(wr1 + 4);
  abuf[0][0] = *(const bf16x8*)(xr0);
  abuf[0][1] = *(const bf16x8*)(xr1);
  abuf[0][2] = *(const bf16x8*)(xr2);

#pragma unroll 2
  for (int t = 0; t < 32; ++t) {
    int cur = t & 1, nxt = cur ^ 1;
    if (t + 1 < 32) {
      int off = (t + 1) * 32;
      wbuf[nxt][0] = nt_load4(wr0 + off);
      wbuf[nxt][1] = nt_load4(wr0 + off + 4);
      wbuf[nxt][2] = nt_load4(wr1 + off);
      wbuf[nxt][3] = nt_load4(wr1 + off + 4);
      abuf[nxt][0] = *(const bf16x8*)(xr0 + off);
      abuf[nxt][1] = *(const bf16x8*)(xr1 + off);
      abuf[nxt][2] = *(const bf16x8*)(xr2 + off);
    }
#pragma unroll
    for (int jf = 0; jf < 2; ++jf) {
      float4 f0 = wbuf[cur][jf * 2], f1 = wbuf[cur][jf * 2 + 1];
      bf16x8 bb;
      bb[0] = (short)f2bf(f0.x); bb[1] = (short)f2bf(f0.y);
      bb[2] = (short)f2bf(f0.z); bb[3] = (short)f2bf(f0.w);
      bb[4] = (short)f2bf(f1.x); bb[5] = (short)f2bf(f1.y);
      bb[6] = (short)f2bf(f1.z); bb[7] = (short)f2bf(f1.w);
      acc[0][jf] = __builtin_amdgcn_mfma_f32_16x16x32_bf16(abuf[cur][0], bb, acc[0][jf], 0, 0, 0);
      acc[1][jf] = __builtin_amdgcn_mfma_f32_16x16x32_bf16(abuf[cur][1], bb, acc[1][jf], 0, 0, 0);
      acc[2][jf] = __builtin_amdgcn_mfma_f32_16x16x32_bf16(abuf[cur][2], bb, acc[2][jf], 0, 0, 0);
    }
  }

  // epilogue: atomic accumulate into G[bt][j]
#pragma unroll
  for (int mf = 0; mf < 3; ++mf)
#pragma unroll
    for (int jf = 0; jf < 2; ++jf) {
      int j = j0 + jf * 16 + lm;
#pragma unroll
      for (int r = 0; r < 4; ++r) {
        int bt = mf * 16 + kg * 4 + r;   // C/D: col=lane&15, row=(lane>>4)*4+r
        atomicAdd(&G[bt * NJ + j], acc[mf][jf][r]);
      }
    }
}

// ---------------- LSTM (one block per batch element; reads G directly) ----------------
__global__ __launch_bounds__(512) void k_lstm(const float* __restrict__ G, const float* __restrict__ Whh,
                                              const float* __restrict__ bih, const float* __restrict__ bhh,
                                              float* __restrict__ hlast) {
  __shared__ float hs[HLL];
  __shared__ float gs[NJ];
  int b = blockIdx.x, j = threadIdx.x;
  float bias = bih[j] + bhh[j];
  float w[HLL];
  const float* wr = Whh + (size_t)j * HLL;
#pragma unroll
  for (int k = 0; k < HLL; k += 4) {
    float4 v = *(const float4*)(wr + k);
    w[k] = v.x; w[k + 1] = v.y; w[k + 2] = v.z; w[k + 3] = v.w;
  }
  if (j < HLL) hs[j] = 0.f;
  float c = 0.f;
  __syncthreads();
  for (int t = 0; t < 12; ++t) {
    float acc = G[(size_t)(b * 12 + t) * NJ + j] + bias;
#pragma unroll
    for (int k = 0; k < HLL; ++k) acc += w[k] * hs[k];
    gs[j] = acc;
    __syncthreads();
    if (j < HLL) {
      float gi = gs[j], gf = gs[HLL + j], gg = gs[2 * HLL + j], go = gs[3 * HLL + j];
      float si = 1.f / (1.f + __expf(-gi));
      float sf = 1.f / (1.f + __expf(-gf));
      float so = 1.f / (1.f + __expf(-go));
      c = sf * c + si * tanhf(gg);
      hs[j] = so * tanhf(c);
    }
    __syncthreads();
  }
  if (j < HLL) hlast[b * HLL + j] = hs[j];
}

// ---------------- FC epilogue ----------------
__global__ __launch_bounds__(256) void k_fc(const float* __restrict__ hlast, const float* __restrict__ Wfc,
                                            const float* __restrict__ bfc, float* __restrict__ out) {
  __shared__ float hl[NJ];
  int tid = threadIdx.x;
  hl[tid] = hlast[tid];
  hl[256 + tid] = hlast[256 + tid];
  __syncthreads();
  int n = blockIdx.x * 256 + tid;
  float a0 = 0.f, a1 = 0.f, a2 = 0.f, a3 = 0.f;
#pragma unroll 8
  for (int k = 0; k < HLL; ++k) {
    float wv = Wfc[(size_t)k * 32768 + n];
    a0 += hl[k] * wv;
    a1 += hl[HLL + k] * wv;
    a2 += hl[2 * HLL + k] * wv;
    a3 += hl[3 * HLL + k] * wv;
  }
  float bb = bfc[n];
  out[n] = a0 + bb;
  out[32768 + n] = a1 + bb;
  out[65536 + n] = a2 + bb;
  out[98304 + n] = a3 + bb;
}

extern "C" void kernel_launch(void* const* d_in, const int* in_sizes, int n_in,
                              void* d_out, int out_size, void* d_ws, size_t ws_size,
                              hipStream_t stream) {
  const float* x     = (const float*)d_in[0];
  const int*   ei    = (const int*)d_in[1];   // int32 (JAX x64 off)
  const float* Wg    = (const float*)d_in[2];
  const float* att_s = (const float*)d_in[3];
  const float* att_d = (const float*)d_in[4];
  const float* b_gat = (const float*)d_in[5];
  const float* Wih   = (const float*)d_in[6];
  const float* Whh   = (const float*)d_in[7];
  const float* bih   = (const float*)d_in[8];
  const float* bhh   = (const float*)d_in[9];
  const float* Wfc   = (const float*)d_in[10];
  const float* bfc   = (const float*)d_in[11];
  float* out = (float*)d_out;

  char* ws = (char*)d_ws;
  unsigned short* h  = (unsigned short*)(ws);      // bf16: 48*4096*64*2 = 25165824
  float* a_s         = (float*)(ws + 25165824);    // 6291456
  float* a_d         = (float*)(ws + 31457280);    // 6291456
  unsigned short* Xb = (unsigned short*)(ws + 37748736); // 25165824 (ends 62914560)
  int* ssrc          = (int*)(ws + 62914560);      // 4096*64*4 = 1048576
  float* G           = (float*)(ws + 63963136);    // 24576*4   = 98304
  float* hlast       = (float*)(ws + 64061440);    // 2048
  int* cursor        = (int*)(ws + 64063488);      // 16384

  hipMemsetAsync(cursor, 0, NN * sizeof(int), stream);
  hipLaunchKernelGGL(k_sp,   dim3(6416),     dim3(256), 0, stream, x, Wg, att_s, att_d, ei, cursor, ssrc, G, h, a_s, a_d);
  hipLaunchKernelGGL(k_gat,  dim3(48 * 128), dim3(256), 0, stream, h, a_s, a_d, cursor, ssrc, b_gat, Xb);
  hipLaunchKernelGGL(k_gemm, dim3(1024),     dim3(256), 0, stream, Xb, Wih, G);
  hipLaunchKernelGGL(k_lstm, dim3(4),        dim3(512), 0, stream, G, Whh, bih, bhh, hlast);
  hipLaunchKernelGGL(k_fc,   dim3(128),      dim3(256), 0, stream, hlast, Wfc, bfc, out);
}